// Round 14
// baseline (168.019 us; speedup 1.0000x reference)
//
#include <hip/hip_runtime.h>
#include <cstdint>
#include <cstddef>

// Problem shape (fixed by setup_inputs): hidden [4,2048,2048] -> M=8192, K=2048, N=2048
#define MDIM 8192
#define NDIM 2048
#define KDIM 2048

constexpr int BM = 128, BN = 256, BK = 64;   // dbuf: 2 x (8KB A + 16KB B) = 48 KB -> 2 blocks/CU

typedef int v4i  __attribute__((ext_vector_type(4)));
typedef int v16i __attribute__((ext_vector_type(16)));

__device__ __forceinline__ void async_ld16(const void* g, void* l) {
    __builtin_amdgcn_global_load_lds(
        (const __attribute__((address_space(1))) int*)g,
        (__attribute__((address_space(3))) int*)l,
        16, 0, 0);
}

// ---------- fused quantize: x fp32 -> int8 (packed u32)  +  W fp32 [K][N] -> int8 [N][K] ----------
__device__ __forceinline__ uint32_t q8(float x, float inv) {
    float q = fminf(fmaxf(rintf(x * inv), -127.f), 127.f);
    return (uint32_t)((int)q) & 0xffu;
}

// W-part first (blocks 0..1023), then x-part: 4096 blocks x 256 threads x 4 chunked float4
#define WBLOCKS ((KDIM / 64) * (NDIM / 64))       // 1024
#define XCHUNK (MDIM * KDIM / 4 / 4)              // float4s per chunk = 1048576
#define XBLOCKS (XCHUNK / 256)                    // 4096 blocks

__global__ void quant_kernel(const float4* __restrict__ x, uint32_t* __restrict__ xq,
                             const float* __restrict__ scale_p,
                             const float* __restrict__ w, uint32_t* __restrict__ wt) {
    __shared__ uint32_t t[64][17];
    const int tid = threadIdx.x;

    if (blockIdx.x >= WBLOCKS) {
        // ---- x quant: thread handles 4 float4s at chunk stride (all accesses coalesced) ----
        int i = (blockIdx.x - WBLOCKS) * 256 + tid;
        float inv = 1.0f / fmaxf(scale_p[0], 1e-8f);
#pragma unroll
        for (int k = 0; k < 4; ++k) {
            float4 v = x[i + k * XCHUNK];
            xq[i + k * XCHUNK] =
                q8(v.x, inv) | (q8(v.y, inv) << 8) | (q8(v.z, inv) << 16) | (q8(v.w, inv) << 24);
        }
        return;
    }

    // ---- W quant + transpose: 64x64 tile per block ----
    const int bid = blockIdx.x;                    // 0..1023
    const int k0 = (bid >> 5) * 64;                // KDIM/64 = 32
    const int n0 = (bid & 31) * 64;                // NDIM/64 = 32
    const int rr  = tid >> 4;                      // 0..15
    const int c4  = (tid & 15) * 4;                // 0..60
#pragma unroll
    for (int p = 0; p < 4; ++p) {
        int r = rr + p * 16;
        float4 v = *(const float4*)&w[(size_t)(k0 + r) * NDIM + n0 + c4];
        uint32_t pk = (uint32_t)((int)rintf(v.x) & 0xff)
                    | ((uint32_t)((int)rintf(v.y) & 0xff) << 8)
                    | ((uint32_t)((int)rintf(v.z) & 0xff) << 16)
                    | ((uint32_t)((int)rintf(v.w) & 0xff) << 24);
        t[r][c4 >> 2] = pk;
    }
    __syncthreads();
    // read side: thread owns column c = rr+p*16, rows c4..c4+3 -> one uint32 out
#pragma unroll
    for (int p = 0; p < 4; ++p) {
        int c = rr + p * 16;
        uint32_t o = 0;
#pragma unroll
        for (int j = 0; j < 4; ++j) {
            uint32_t b = (t[c4 + j][c >> 2] >> ((c & 3) * 8)) & 0xffu;
            o |= b << (j * 8);
        }
        wt[((size_t)(n0 + c) * KDIM + k0 + c4) >> 2] = o;
    }
}

// ---------- i8 GEMM: C = A * Bt^T + bias; 128x256, 512 thr, R0 sync, mfma 32x32x32 ----------
// R12 retry with the conflict fixed: LDS holds each (64-row panel, 32-row sub-block i,
// k-step s) as a CONTIGUOUS 1024 B block:
//   offset(r,c) = (r>>6)*4096 + (((r>>5)&1)*2 + (c>>1))*1024 + (r&31)*32 + (c&1)*16
// so each fragment ds_read_b128 covers a full 1024 B block (lane: l31*32 + l5*16 — 64
// distinct 16B slots, zero conflicts by construction). R12's row-major layout put 32x32
// reads on 2-of-4 slots/row -> 4.19M conflicts, +6 us; this layout removes them while
// keeping the proven R0 sync structure. Staging inverts the same bijection: wave w's
// linear async dest (w*1024 + lane*16) <- global row (w>>2)*64+((w>>1)&1)*32+(lane>>1),
// col (w&1)*32+(lane&1)*16. Fragment + C/D mappings HW-validated by R12 (absmax 0).
// launch_bounds(512,4) = 128-reg cap (unified VGPR+AGPR): acc 64 + frags ~32 fits.
__global__ __launch_bounds__(512, 4)
void gemm_i8_kernel(const int8_t* __restrict__ A,   // [M][K] int8
                    const int8_t* __restrict__ Bt,  // [N][K] int8
                    const float* __restrict__ bias, // [N]
                    float* __restrict__ C) {        // [M][N] fp32
    __shared__ alignas(16) int8_t lA[2][BM * BK];   // 2 x 8 KB
    __shared__ alignas(16) int8_t lB[2][BN * BK];   // 2 x 16 KB

    const int tid  = threadIdx.x;
    const int lane = tid & 63;
    const int wave = tid >> 6;           // 0..7
    const int wm   = wave & 1;           // A panel: 64 rows
    const int wn   = wave >> 1;          // B panel: 64 rows (0..3)

    // XCD-aware bijective swizzle: 512 blocks -> 64 per XCD = 8 m-panels x 8 n-panels,
    // n fastest so A-panels are shared by consecutive co-resident blocks on one XCD.
    const int bidlin = blockIdx.y * gridDim.x + blockIdx.x;   // 0..511
    const int xcd    = bidlin & 7;
    const int idx    = bidlin >> 3;                            // 0..63
    const int m0     = (xcd * 8 + (idx >> 3)) * BM;            // 64 m-panels
    const int n0     = (idx & 7) * BN;                         // 8 n-panels

    // staging (block-contiguous layout): wave w owns 1024B block w of A, blocks w & w+8 of B
    const int srow = (wave >> 2) * 64 + ((wave >> 1) & 1) * 32 + (lane >> 1);  // 0..127
    const int scol = (wave & 1) * 32 + (lane & 1) * 16;
    const int8_t* gA = A  + (size_t)(m0 + srow) * KDIM + scol;
    const int8_t* gB = Bt + (size_t)(n0 + srow) * KDIM + scol;   // B rows 128..255: +128*KDIM
    const int lwo = wave * 1024;

    // fragment reads (32x32x32): lane l31 = row, l5 = 16B k-chunk within the k-step
    const int l31 = lane & 31;
    const int l5  = lane >> 5;
    const int rdo = l31 * 32 + l5 * 16;
    const int aB  = wm * 4096 + rdo;     // + (i*2+s)*1024
    const int bB  = wn * 4096 + rdo;

    v16i acc[2][2];
#pragma unroll
    for (int i = 0; i < 2; ++i)
#pragma unroll
        for (int j = 0; j < 2; ++j)
            acc[i][j] = (v16i){0,0,0,0, 0,0,0,0, 0,0,0,0, 0,0,0,0};

#define STAGE(buf, kof)                                                        \
    do {                                                                       \
        async_ld16(gA + (kof), &lA[buf][lwo]);                                 \
        async_ld16(gB + (kof), &lB[buf][lwo]);                                 \
        async_ld16(gB + (kof) + (size_t)128 * KDIM, &lB[buf][lwo + 8192]);     \
    } while (0)

    // k-step s: 4 contiguous-block reads + 4 x mfma_i32_32x32x32_i8 (2x2 sub-tiles)
#define KSTEP(buf, s)                                                          \
    do {                                                                       \
        v4i a0 = *(const v4i*)&lA[buf][aB + (s) * 1024];                       \
        v4i a1 = *(const v4i*)&lA[buf][aB + (2 + (s)) * 1024];                 \
        v4i b0 = *(const v4i*)&lB[buf][bB + (s) * 1024];                       \
        v4i b1 = *(const v4i*)&lB[buf][bB + (2 + (s)) * 1024];                 \
        acc[0][0] = __builtin_amdgcn_mfma_i32_32x32x32_i8(a0, b0, acc[0][0], 0, 0, 0); \
        acc[0][1] = __builtin_amdgcn_mfma_i32_32x32x32_i8(a0, b1, acc[0][1], 0, 0, 0); \
        acc[1][0] = __builtin_amdgcn_mfma_i32_32x32x32_i8(a1, b0, acc[1][0], 0, 0, 0); \
        acc[1][1] = __builtin_amdgcn_mfma_i32_32x32x32_i8(a1, b1, acc[1][1], 0, 0, 0); \
    } while (0)

#define COMPUTE(buf)                                                           \
    do {                                                                       \
        KSTEP(buf, 0);                                                         \
        KSTEP(buf, 1);                                                         \
    } while (0)

    STAGE(0, 0);
    int kof = BK;
    for (int it = 0; it < KDIM / BK - 1; ++it) {
        __syncthreads();                 // drains vmcnt: tile `it` visible; buf (it+1)&1 free
        STAGE((it + 1) & 1, kof);        // prefetch next tile (flies during compute)
        kof += BK;
        COMPUTE(it & 1);
    }
    __syncthreads();
    COMPUTE((KDIM / BK - 1) & 1);

    // epilogue: 32x32 C/D layout (HW-verified m74/m101 + R12 absmax 0, dtype-indep):
    // col = lane&31, row = (reg&3) + 8*(reg>>2) + 4*(lane>>5)
    const int crow = m0 + wm * 64 + 4 * l5;
    const int ccol = n0 + wn * 64 + l31;
    float bj[2] = { bias[ccol], bias[ccol + 32] };
#pragma unroll
    for (int i = 0; i < 2; ++i)
#pragma unroll
        for (int j = 0; j < 2; ++j)
#pragma unroll
            for (int r = 0; r < 16; ++r)
                C[(size_t)(crow + i * 32 + (r & 3) + 8 * (r >> 2)) * NDIM + (ccol + j * 32)]
                    = (float)acc[i][j][r] + bj[j];
}

extern "C" void kernel_launch(void* const* d_in, const int* in_sizes, int n_in,
                              void* d_out, int out_size, void* d_ws, size_t ws_size,
                              hipStream_t stream) {
    const float* x    = (const float*)d_in[0];   // [8192, 2048] fp32
    const float* w    = (const float*)d_in[1];   // [2048, 2048] fp32 (integer-valued)
    const float* xs   = (const float*)d_in[2];   // scalar
    const float* bias = (const float*)d_in[3];   // [2048]
    float* out = (float*)d_out;                  // [8192, 2048] fp32

    int8_t* xq = (int8_t*)d_ws;                          // 16 MB
    int8_t* wt = xq + (size_t)MDIM * KDIM;               //  4 MB

    quant_kernel<<<WBLOCKS + XBLOCKS, 256, 0, stream>>>(
        (const float4*)x, (uint32_t*)xq, xs, w, (uint32_t*)wt);
    gemm_i8_kernel<<<dim3(NDIM / BN, MDIM / BM), 512, 0, stream>>>(xq, wt, bias, out);
}

// Round 15
// 164.128 us; speedup vs baseline: 1.0237x; 1.0237x over previous
//
#include <hip/hip_runtime.h>
#include <cstdint>
#include <cstddef>

// Problem shape (fixed by setup_inputs): hidden [4,2048,2048] -> M=8192, K=2048, N=2048
#define MDIM 8192
#define NDIM 2048
#define KDIM 2048

constexpr int BM = 128, BN = 256, BK = 64;   // dbuf: 2 x (8KB A + 16KB B) = 48 KB -> 2 blocks/CU

typedef int v4i __attribute__((ext_vector_type(4)));

__device__ __forceinline__ void async_ld16(const void* g, void* l) {
    __builtin_amdgcn_global_load_lds(
        (const __attribute__((address_space(1))) int*)g,
        (__attribute__((address_space(3))) int*)l,
        16, 0, 0);
}

// ---------- fused quantize: x fp32 -> int8 (packed u32)  +  W fp32 [K][N] -> int8 [N][K] ----------
__device__ __forceinline__ uint32_t q8(float x, float inv) {
    float q = fminf(fmaxf(rintf(x * inv), -127.f), 127.f);
    return (uint32_t)((int)q) & 0xffu;
}

// W-part first (blocks 0..1023), then x-part: 4096 blocks x 256 threads x 4 chunked float4
#define WBLOCKS ((KDIM / 64) * (NDIM / 64))       // 1024
#define XCHUNK (MDIM * KDIM / 4 / 4)              // float4s per chunk = 1048576
#define XBLOCKS (XCHUNK / 256)                    // 4096 blocks

__global__ void quant_kernel(const float4* __restrict__ x, uint32_t* __restrict__ xq,
                             const float* __restrict__ scale_p,
                             const float* __restrict__ w, uint32_t* __restrict__ wt) {
    __shared__ uint32_t t[64][17];
    const int tid = threadIdx.x;

    if (blockIdx.x >= WBLOCKS) {
        // ---- x quant: thread handles 4 float4s at chunk stride (all accesses coalesced) ----
        int i = (blockIdx.x - WBLOCKS) * 256 + tid;
        float inv = 1.0f / fmaxf(scale_p[0], 1e-8f);
#pragma unroll
        for (int k = 0; k < 4; ++k) {
            float4 v = x[i + k * XCHUNK];
            xq[i + k * XCHUNK] =
                q8(v.x, inv) | (q8(v.y, inv) << 8) | (q8(v.z, inv) << 16) | (q8(v.w, inv) << 24);
        }
        return;
    }

    // ---- W quant + transpose: 64x64 tile per block ----
    const int bid = blockIdx.x;                    // 0..1023
    const int k0 = (bid >> 5) * 64;                // KDIM/64 = 32
    const int n0 = (bid & 31) * 64;                // NDIM/64 = 32
    const int rr  = tid >> 4;                      // 0..15
    const int c4  = (tid & 15) * 4;                // 0..60
#pragma unroll
    for (int p = 0; p < 4; ++p) {
        int r = rr + p * 16;
        float4 v = *(const float4*)&w[(size_t)(k0 + r) * NDIM + n0 + c4];
        uint32_t pk = (uint32_t)((int)rintf(v.x) & 0xff)
                    | ((uint32_t)((int)rintf(v.y) & 0xff) << 8)
                    | ((uint32_t)((int)rintf(v.z) & 0xff) << 16)
                    | ((uint32_t)((int)rintf(v.w) & 0xff) << 24);
        t[r][c4 >> 2] = pk;
    }
    __syncthreads();
    // read side: thread owns column c = rr+p*16, rows c4..c4+3 -> one uint32 out
#pragma unroll
    for (int p = 0; p < 4; ++p) {
        int c = rr + p * 16;
        uint32_t o = 0;
#pragma unroll
        for (int j = 0; j < 4; ++j) {
            uint32_t b = (t[c4 + j][c >> 2] >> ((c & 3) * 8)) & 0xffu;
            o |= b << (j * 8);
        }
        wt[((size_t)(n0 + c) * KDIM + k0 + c4) >> 2] = o;
    }
}

// ---------- i8 GEMM: C = A * Bt^T + bias; BM=128 x BN=256, 512 thr, R0 sync structure ----------
// FINAL (best measured: 163.4 us total; gemm 45-48 us, MfmaUtil 28-30, FETCH 24.7 MB,
// SQ_LDS_BANK_CONFLICT 0, no spill). Session map:
//  - launch_bounds(512,4) = 128-reg cap (unified VGPR+AGPR file) -> no spill, 2 blocks/CU.
//    (512,6) = 85-reg cap spilled acc -> 1 GB scratch, 2x slower (R6).
//  - 16 waves/CU resident is necessary (8-wave configs +15-20% slower: R1/R3/R4).
//  - Schedule surgery (counted vmcnt, 4/8-phase, 4-deep rings) null on this kernel (R1-R4).
//  - 256^2/16-wave lockstep regressed (R8); fused x-quant thrashed L2, 2x (R10).
//  - mfma 32x32x32: +12% ubench rate but BOTH derived layouts (row-major-XOR R12,
//    block-contiguous R14) hit exactly 4 extra LDS cycles per ds_read_b128 (4.19M
//    conflicts, +5 us) — 32-row fragment read geometry conflicts under a bank-phase
//    mechanism the 16-row pattern avoids. Shape closed.
// LDS row = 64B = 4 x 16B chunks; chunk c of row r stored at c ^ ((r>>1)&3).
__global__ __launch_bounds__(512, 4)
void gemm_i8_kernel(const int8_t* __restrict__ A,   // [M][K] int8
                    const int8_t* __restrict__ Bt,  // [N][K] int8
                    const float* __restrict__ bias, // [N]
                    float* __restrict__ C) {        // [M][N] fp32
    __shared__ alignas(16) int8_t lA[2][BM * BK];   // 2 x 8 KB
    __shared__ alignas(16) int8_t lB[2][BN * BK];   // 2 x 16 KB

    const int tid  = threadIdx.x;
    const int lane = tid & 63;
    const int wave = tid >> 6;           // 0..7
    const int wm   = wave & 1;           // M-half: 64 rows
    const int wn   = wave >> 1;          // N-quarter: 64 cols

    // XCD-aware bijective swizzle: 512 blocks -> 64 per XCD = 8 m-panels x 8 n-panels,
    // n fastest so A-panels are shared by consecutive co-resident blocks on one XCD.
    const int bidlin = blockIdx.y * gridDim.x + blockIdx.x;   // 0..511
    const int xcd    = bidlin & 7;
    const int idx    = bidlin >> 3;                            // 0..63
    const int m0     = (xcd * 8 + (idx >> 3)) * BM;            // 64 m-panels
    const int n0     = (idx & 7) * BN;                         // 8 n-panels

    // staging: A wave covers rows [wave*16,+16) (1 issue); B wave covers [wave*32,+32) (2 issues)
    const int srow = lane >> 2;                       // 0..15
    const int schk = (lane & 3) ^ ((srow >> 1) & 3);  // swizzled source chunk
    const int8_t* gA = A  + (size_t)(m0 + wave * 16 + srow) * KDIM + schk * 16;
    const int8_t* gB = Bt + (size_t)(n0 + wave * 32 + srow) * KDIM + schk * 16;
    const int lwoA = wave * 1024;
    const int lwoB = wave * 2048;

    // fragments: lane reads row (.. + lr), global chunk quad -> LDS chunk quad^((lr>>1)&3)
    const int quad = lane >> 4;
    const int lr   = lane & 15;
    const int fchk = (quad ^ ((lr >> 1) & 3)) * 16;
    const int aoff = (wm * 64 + lr) * BK + fchk;
    const int boff = (wn * 64 + lr) * BK + fchk;

    v4i acc[4][4];
#pragma unroll
    for (int i = 0; i < 4; ++i)
#pragma unroll
        for (int j = 0; j < 4; ++j)
            acc[i][j] = (v4i){0, 0, 0, 0};

#define STAGE(buf, kof)                                                        \
    do {                                                                       \
        async_ld16(gA + (kof), &lA[buf][lwoA]);                                \
        async_ld16(gB + (kof), &lB[buf][lwoB]);                                \
        async_ld16(gB + (kof) + (size_t)16 * KDIM, &lB[buf][lwoB + 1024]);     \
    } while (0)

#define COMPUTE(buf)                                                           \
    do {                                                                       \
        v4i af[4], bf[4];                                                      \
        _Pragma("unroll")                                                      \
        for (int i = 0; i < 4; ++i)                                            \
            af[i] = *(const v4i*)&lA[buf][aoff + i * 1024];                    \
        _Pragma("unroll")                                                      \
        for (int j = 0; j < 4; ++j)                                            \
            bf[j] = *(const v4i*)&lB[buf][boff + j * 1024];                    \
        _Pragma("unroll")                                                      \
        for (int i = 0; i < 4; ++i)                                            \
            _Pragma("unroll")                                                  \
            for (int j = 0; j < 4; ++j)                                        \
                acc[i][j] = __builtin_amdgcn_mfma_i32_16x16x64_i8(             \
                    af[i], bf[j], acc[i][j], 0, 0, 0);                         \
    } while (0)

    STAGE(0, 0);
    int kof = BK;
    for (int it = 0; it < KDIM / BK - 1; ++it) {
        __syncthreads();                 // drains vmcnt: tile `it` visible; buf (it+1)&1 free
        STAGE((it + 1) & 1, kof);        // prefetch next tile (flies during compute)
        kof += BK;
        COMPUTE(it & 1);
    }
    __syncthreads();
    COMPUTE((KDIM / BK - 1) & 1);

    // epilogue: C/D layout col = lane&15, row = quad*4 + reg (verified, dtype-indep)
    const int crow = m0 + wm * 64 + quad * 4;
    const int ccol = n0 + wn * 64 + lr;
    float bj[4];
#pragma unroll
    for (int j = 0; j < 4; ++j) bj[j] = bias[ccol + j * 16];
#pragma unroll
    for (int i = 0; i < 4; ++i)
#pragma unroll
        for (int j = 0; j < 4; ++j)
#pragma unroll
            for (int r = 0; r < 4; ++r)
                C[(size_t)(crow + i * 16 + r) * NDIM + (ccol + j * 16)] = (float)acc[i][j][r] + bj[j];
}

extern "C" void kernel_launch(void* const* d_in, const int* in_sizes, int n_in,
                              void* d_out, int out_size, void* d_ws, size_t ws_size,
                              hipStream_t stream) {
    const float* x    = (const float*)d_in[0];   // [8192, 2048] fp32
    const float* w    = (const float*)d_in[1];   // [2048, 2048] fp32 (integer-valued)
    const float* xs   = (const float*)d_in[2];   // scalar
    const float* bias = (const float*)d_in[3];   // [2048]
    float* out = (float*)d_out;                  // [8192, 2048] fp32

    int8_t* xq = (int8_t*)d_ws;                          // 16 MB
    int8_t* wt = xq + (size_t)MDIM * KDIM;               //  4 MB

    quant_kernel<<<WBLOCKS + XBLOCKS, 256, 0, stream>>>(
        (const float4*)x, (uint32_t*)xq, xs, w, (uint32_t*)wt);
    gemm_i8_kernel<<<dim3(NDIM / BN, MDIM / BM), 512, 0, stream>>>(xq, wt, bias, out);
}